// Round 7
// baseline (17.458 us; speedup 1.0000x reference)
//
#include <hip/hip_runtime.h>

#define SEQ 512
#define DIM 1024
#define HD  512
#define NSPAN 4068   // 505*8 + 28
#define NFULL 4040   // rows 0..504 * 8
#define MAGIC 0x13371337
#define BPB 64       // blocks per batch (512 rows / 8 rows per block)

__device__ __forceinline__ float dot4(const float4 a, const float4 b) {
    return a.x * b.x + a.y * b.y + a.z * b.z + a.w * b.w;
}

// Fused: per-token dots + per-batch softmax, one dispatch.
// 2048 blocks x 512 threads; block k owns rows [8k, 8k+8) (1 row/wave),
// batch b = k>>6. Cross-block visibility uses ONLY relaxed agent-scope
// atomics (sc1, coherence-point ops) -- no seq_cst, no cache-flush fences
// (R3's 70us lesson). Last finisher of a batch claims its softmax.
__global__ __launch_bounds__(512) void fused_kernel(
    const float* __restrict__ emb,    // [B*S, 1024]
    const int*   __restrict__ ttid,   // [B*S]
    const int*   __restrict__ amask,  // [B*S]
    const float* __restrict__ W,      // [512]
    const float* __restrict__ biasp,  // [1]
    float* __restrict__ out,          // [B, NSPAN]
    float* sdot,                      // [B*S]  (protocol data, sc1 ops)
    float* edot,                      // [B*S]
    int*   flags,                     // [2048]
    int*   claim)                     // [32]
{
    const int tid  = threadIdx.x;
    const int wave = tid >> 6;        // 0..7
    const int lane = tid & 63;
    const int blk  = blockIdx.x;
    const int b    = blk >> 6;
    const int row  = blk * 8 + wave;  // 16384 rows

    // ---- dot phase: one row per wave; skip unmasked rows (exp underflows
    // to exactly 0 for their spans -- validated R4-R6) ----
    const int m = ttid[row] * amask[row];
    if (m != 0) {
        const int d0 = lane * 4;
        const float4 w0 = *reinterpret_cast<const float4*>(W + d0);
        const float4 w1 = *reinterpret_cast<const float4*>(W + 256 + d0);
        const float* p = emb + (size_t)row * DIM;
        const float4 v0 = *reinterpret_cast<const float4*>(p + d0);
        const float4 v1 = *reinterpret_cast<const float4*>(p + 256 + d0);
        const float4 u0 = *reinterpret_cast<const float4*>(p + HD + d0);
        const float4 u1 = *reinterpret_cast<const float4*>(p + HD + 256 + d0);
        float s = dot4(v0, w0) + dot4(v1, w1);
        float e = dot4(u0, w0) + dot4(u1, w1);
#pragma unroll
        for (int off = 32; off >= 1; off >>= 1) {
            s += __shfl_xor(s, off, 64);
            e += __shfl_xor(e, off, 64);
        }
        if (lane == 0) {
            __hip_atomic_store(&sdot[row], s, __ATOMIC_RELAXED, __HIP_MEMORY_SCOPE_AGENT);
            __hip_atomic_store(&edot[row], e, __ATOMIC_RELAXED, __HIP_MEMORY_SCOPE_AGENT);
        }
    } else if (lane == 0) {           // keep zeros: NaN-garbage must not leak in
        __hip_atomic_store(&sdot[row], 0.f, __ATOMIC_RELAXED, __HIP_MEMORY_SCOPE_AGENT);
        __hip_atomic_store(&edot[row], 0.f, __ATOMIC_RELAXED, __HIP_MEMORY_SCOPE_AGENT);
    }

    __syncthreads();   // compiler drains vmcnt(0) before s_barrier: all 8
                       // waves' sc1 data stores are at the coherence point

    // ---- publish flag, check batch completion, claim ----
    __shared__ int s_claimed;
    if (wave == 0) {
        if (lane == 0)
            __hip_atomic_store(&flags[blk], MAGIC, __ATOMIC_RELAXED, __HIP_MEMORY_SCOPE_AGENT);
        asm volatile("s_waitcnt vmcnt(0)" ::: "memory");   // own flag visible
        const int f = __hip_atomic_load(&flags[(b << 6) + lane],
                                        __ATOMIC_RELAXED, __HIP_MEMORY_SCOPE_AGENT);
        const unsigned long long all = __ballot(f == MAGIC);
        if (lane == 0) {
            int cl = 0;
            if (all == 0xFFFFFFFFFFFFFFFFULL) {
                const int old = __hip_atomic_exchange(&claim[b], MAGIC,
                                                      __ATOMIC_RELAXED,
                                                      __HIP_MEMORY_SCOPE_AGENT);
                cl = (old != MAGIC) ? 1 : 0;
            }
            s_claimed = cl;
        }
    }
    __syncthreads();
    if (!s_claimed) return;

    // ---- claimer: reset flags for next replay, then batch-b softmax ----
    if (tid < BPB)
        __hip_atomic_store(&flags[(b << 6) + tid], 0, __ATOMIC_RELAXED, __HIP_MEMORY_SCOPE_AGENT);

    __shared__ float sd[SEQ], ed[SEQ], mk[SEQ];
    __shared__ float red[8];

    const float bias = biasp[0];
    if (tid < SEQ) {
        sd[tid] = __hip_atomic_load(&sdot[b * SEQ + tid], __ATOMIC_RELAXED, __HIP_MEMORY_SCOPE_AGENT);
        ed[tid] = __hip_atomic_load(&edot[b * SEQ + tid], __ATOMIC_RELAXED, __HIP_MEMORY_SCOPE_AGENT);
        mk[tid] = (float)(ttid[b * SEQ + tid] * amask[b * SEQ + tid]);
    }
    __syncthreads();

    float ez[8];
    float lsum = 0.f;
#pragma unroll
    for (int i = 0; i < 8; ++i) {
        const int n = tid + 512 * i;
        ez[i] = 0.f;
        if (n < NSPAN) {
            int si, ei;
            if (n < NFULL) {
                si = n >> 3;
                ei = si + (n & 7);
            } else {                  // 28-entry tail: rows 505..511
                int mm = n - NFULL;
                int t = 0, cnt = 7, off = 0;
                while (mm >= off + cnt) { off += cnt; --cnt; ++t; }
                si = 505 + t;
                ei = si + (mm - off);
            }
            float lg = sd[si] + ed[ei] + bias;
            lg -= 1.0e7f * (1.0f - mk[si] * mk[ei]);   // reference masking
            ez[i] = __expf(lg);                        // masked -> exactly 0
            lsum += ez[i];
        }
    }

#pragma unroll
    for (int off = 32; off >= 1; off >>= 1)
        lsum += __shfl_xor(lsum, off, 64);
    if (lane == 0) red[wave] = lsum;
    __syncthreads();
    float tot = red[0];
#pragma unroll
    for (int i = 1; i < 8; ++i) tot += red[i];
    const float inv = 1.0f / tot;

#pragma unroll
    for (int i = 0; i < 8; ++i) {
        const int n = tid + 512 * i;
        if (n < NSPAN)
            out[(size_t)b * NSPAN + n] = ez[i] * inv;
    }

    // release claim last (benign idempotent race -- see journal)
    __syncthreads();
    if (tid == 0)
        __hip_atomic_store(&claim[b], 0, __ATOMIC_RELAXED, __HIP_MEMORY_SCOPE_AGENT);
}

extern "C" void kernel_launch(void* const* d_in, const int* in_sizes, int n_in,
                              void* d_out, int out_size, void* d_ws, size_t ws_size,
                              hipStream_t stream) {
    const float* emb   = (const float*)d_in[0];  // [32,512,1024] f32
    const int*   ttid  = (const int*)d_in[1];    // [32,512]
    const int*   amask = (const int*)d_in[2];    // [32,512]
    const float* W     = (const float*)d_in[3];  // [512,1]
    const float* biasp = (const float*)d_in[4];  // [1]
    float*       out   = (float*)d_out;          // [32,4068]

    float* sdot  = (float*)d_ws;                 // 16384 floats
    float* edot  = sdot + 32 * SEQ;              // 16384 floats
    int*   flags = (int*)(edot + 32 * SEQ);      // 2048 ints
    int*   claim = flags + 2048;                 // 32 ints

    fused_kernel<<<dim3(2048), dim3(512), 0, stream>>>(
        emb, ttid, amask, W, biasp, out, sdot, edot, flags, claim);
}

// Round 8
// 16.496 us; speedup vs baseline: 1.0583x; 1.0583x over previous
//
#include <hip/hip_runtime.h>

#define SEQ 512
#define DIM 1024
#define HD  512
#define NSPAN 4068   // 505*8 + 28
#define NFULL 4040   // rows 0..504 * 8

__device__ __forceinline__ float dot4(const float4 a, const float4 b) {
    return a.x * b.x + a.y * b.y + a.z * b.z + a.w * b.w;
}

// Fully fused, zero cross-block communication: one block per batch.
// 32 blocks x 1024 threads (16 waves). Phase A: masks -> LDS. Phase B:
// each wave owns a 32-row stripe, ballots its unmasked rows, computes
// dots (4x float4 vs W in registers) into LDS. Phase C: in-block
// masked softmax over 4068 spans (no max subtraction: logits O(5),
// masked spans underflow to exactly 0 -- validated R4-R7).
__global__ __launch_bounds__(1024) void fused_kernel(
    const float* __restrict__ emb,    // [B*S, 1024]
    const int*   __restrict__ ttid,   // [B*S]
    const int*   __restrict__ amask,  // [B*S]
    const float* __restrict__ W,      // [512]
    const float* __restrict__ biasp,  // [1]
    float* __restrict__ out)          // [B, NSPAN]
{
    const int b    = blockIdx.x;
    const int tid  = threadIdx.x;
    const int wave = tid >> 6;        // 0..15
    const int lane = tid & 63;

    __shared__ float sd[SEQ], ed[SEQ], mk[SEQ];
    __shared__ float red[16];

    // ---- phase A: masks into LDS, zero-init dots ----
    if (tid < SEQ) {
        const int m = ttid[b * SEQ + tid] * amask[b * SEQ + tid];
        mk[tid] = (float)m;
        sd[tid] = 0.f;
        ed[tid] = 0.f;
    }
    __syncthreads();

    // ---- phase B: dots for unmasked rows; wave w owns rows [32w,32w+32) ----
    {
        const int r0 = wave * 32;
        const unsigned long long mb =
            __ballot((lane < 32) ? (mk[r0 + lane] != 0.f) : false);
        unsigned long long mbits = mb;

        const int d0 = lane * 4;
        const float4 w0 = *reinterpret_cast<const float4*>(W + d0);
        const float4 w1 = *reinterpret_cast<const float4*>(W + 256 + d0);

        while (mbits) {
            const int r = __ffsll(mbits) - 1;
            mbits &= mbits - 1;
            const float* p = emb + ((size_t)b * SEQ + r0 + r) * DIM;
            const float4 v0 = *reinterpret_cast<const float4*>(p + d0);
            const float4 v1 = *reinterpret_cast<const float4*>(p + 256 + d0);
            const float4 u0 = *reinterpret_cast<const float4*>(p + HD + d0);
            const float4 u1 = *reinterpret_cast<const float4*>(p + HD + 256 + d0);
            float s = dot4(v0, w0) + dot4(v1, w1);
            float e = dot4(u0, w0) + dot4(u1, w1);
#pragma unroll
            for (int off = 32; off >= 1; off >>= 1) {
                s += __shfl_xor(s, off, 64);
                e += __shfl_xor(e, off, 64);
            }
            if (lane == 0) { sd[r0 + r] = s; ed[r0 + r] = e; }
        }
    }
    __syncthreads();

    // ---- phase C: masked softmax over spans ----
    const float bias = biasp[0];
    float ez[4];
    float lsum = 0.f;
#pragma unroll
    for (int i = 0; i < 4; ++i) {
        const int n = tid + 1024 * i;
        ez[i] = 0.f;
        if (n < NSPAN) {
            int si, ei;
            if (n < NFULL) {
                si = n >> 3;
                ei = si + (n & 7);
            } else {                  // 28-entry tail: rows 505..511
                int mm = n - NFULL;
                int t = 0, cnt = 7, off = 0;
                while (mm >= off + cnt) { off += cnt; --cnt; ++t; }
                si = 505 + t;
                ei = si + (mm - off);
            }
            float lg = sd[si] + ed[ei] + bias;
            lg -= 1.0e7f * (1.0f - mk[si] * mk[ei]);   // reference masking
            ez[i] = __expf(lg);                        // masked -> exactly 0
            lsum += ez[i];
        }
    }

#pragma unroll
    for (int off = 32; off >= 1; off >>= 1)
        lsum += __shfl_xor(lsum, off, 64);
    if (lane == 0) red[wave] = lsum;
    __syncthreads();
    float tot = red[0];
#pragma unroll
    for (int i = 1; i < 16; ++i) tot += red[i];
    const float inv = 1.0f / tot;

#pragma unroll
    for (int i = 0; i < 4; ++i) {
        const int n = tid + 1024 * i;
        if (n < NSPAN)
            out[(size_t)b * NSPAN + n] = ez[i] * inv;
    }
}

extern "C" void kernel_launch(void* const* d_in, const int* in_sizes, int n_in,
                              void* d_out, int out_size, void* d_ws, size_t ws_size,
                              hipStream_t stream) {
    const float* emb   = (const float*)d_in[0];  // [32,512,1024] f32
    const int*   ttid  = (const int*)d_in[1];    // [32,512]
    const int*   amask = (const int*)d_in[2];    // [32,512]
    const float* W     = (const float*)d_in[3];  // [512,1]
    const float* biasp = (const float*)d_in[4];  // [1]
    float*       out   = (float*)d_out;          // [32,4068]

    fused_kernel<<<dim3(32), dim3(1024), 0, stream>>>(
        emb, ttid, amask, W, biasp, out);
}

// Round 9
// 12.428 us; speedup vs baseline: 1.4048x; 1.3274x over previous
//
#include <hip/hip_runtime.h>

#define SEQ 512
#define DIM 1024
#define HD  512
#define NSPAN 4068   // 505*8 + 28
#define NFULL 4040   // rows 0..504 * 8

__device__ __forceinline__ float dot4(const float4 a, const float4 b) {
    return a.x * b.x + a.y * b.y + a.z * b.z + a.w * b.w;
}

// Kernel 1: per-token dot products vs W, one row per wave (max TLP).
// Masked rows get a {-1e30,-1e30} sentinel: their spans' exp underflows to
// exactly 0, identical to the reference's -1e7 masking after softmax
// (validated R4-R8). Unmasked rows (~25%) read their 4 KB embedding row.
__global__ __launch_bounds__(256) void dot_kernel(
    const float* __restrict__ emb,   // [B*S, 1024]
    const int*   __restrict__ ttid,  // [B*S]
    const int*   __restrict__ amask, // [B*S]
    const float* __restrict__ W,     // [512]
    float2* __restrict__ sed)        // [B*S] packed {sdot, edot}
{
    const int tid  = threadIdx.x;
    const int wave = tid >> 6;
    const int lane = tid & 63;
    const int row  = blockIdx.x * 4 + wave;          // 16384 rows

    const int m = ttid[row] * amask[row];            // wave-uniform
    if (m == 0) {
        if (lane == 0) sed[row] = make_float2(-1e30f, -1e30f);
        return;
    }

    const int d0 = lane * 4;                         // 0..252
    const float4 w0 = *reinterpret_cast<const float4*>(W + d0);
    const float4 w1 = *reinterpret_cast<const float4*>(W + 256 + d0);

    const float* p = emb + (size_t)row * DIM;
    const float4 v0 = *reinterpret_cast<const float4*>(p + d0);
    const float4 v1 = *reinterpret_cast<const float4*>(p + 256 + d0);
    const float4 u0 = *reinterpret_cast<const float4*>(p + HD + d0);
    const float4 u1 = *reinterpret_cast<const float4*>(p + HD + 256 + d0);

    float s = dot4(v0, w0) + dot4(v1, w1);
    float e = dot4(u0, w0) + dot4(u1, w1);

#pragma unroll
    for (int off = 32; off >= 1; off >>= 1) {
        s += __shfl_xor(s, off, 64);
        e += __shfl_xor(e, off, 64);
    }
    if (lane == 0) sed[row] = make_float2(s, e);
}

// Kernel 2: per-batch softmax over 4068 banded spans. No mask inputs
// needed (sentinel encodes masking). Single 4 KB coalesced load, exp
// without max subtraction (logits O(5); masked -> exact 0), block sum,
// normalized write.
__global__ __launch_bounds__(1024) void softmax_kernel(
    const float* __restrict__ sedf,   // [B, S] as flat floats [s0,e0,s1,e1,...]
    const float* __restrict__ biasp,  // [1]
    float* __restrict__ out)          // [B, NSPAN]
{
    const int b    = blockIdx.x;
    const int tid  = threadIdx.x;
    const int wave = tid >> 6;
    const int lane = tid & 63;

    __shared__ float se[2 * SEQ];     // interleaved [s,e] per row
    __shared__ float red[16];

    se[tid] = sedf[b * 2 * SEQ + tid];    // 1024 floats, one per thread
    __syncthreads();

    const float bias = biasp[0];
    float ez[4];
    float lsum = 0.f;
#pragma unroll
    for (int i = 0; i < 4; ++i) {
        const int n = tid + 1024 * i;
        ez[i] = 0.f;
        if (n < NSPAN) {
            int si, ei;
            if (n < NFULL) {
                si = n >> 3;
                ei = si + (n & 7);
            } else {                  // 28-entry tail: rows 505..511
                int mm = n - NFULL;
                int t = 0, cnt = 7, off = 0;
                while (mm >= off + cnt) { off += cnt; --cnt; ++t; }
                si = 505 + t;
                ei = si + (mm - off);
            }
            // masked rows carry -1e30 -> exp underflows to exactly 0
            const float lg = se[2 * si] + se[2 * ei + 1] + bias;
            ez[i] = __expf(lg);
            lsum += ez[i];
        }
    }

#pragma unroll
    for (int off = 32; off >= 1; off >>= 1)
        lsum += __shfl_xor(lsum, off, 64);
    if (lane == 0) red[wave] = lsum;
    __syncthreads();
    float tot = red[0];
#pragma unroll
    for (int i = 1; i < 16; ++i) tot += red[i];
    const float inv = 1.0f / tot;

#pragma unroll
    for (int i = 0; i < 4; ++i) {
        const int n = tid + 1024 * i;
        if (n < NSPAN)
            out[(size_t)b * NSPAN + n] = ez[i] * inv;
    }
}

extern "C" void kernel_launch(void* const* d_in, const int* in_sizes, int n_in,
                              void* d_out, int out_size, void* d_ws, size_t ws_size,
                              hipStream_t stream) {
    const float* emb   = (const float*)d_in[0];  // [32,512,1024] f32
    const int*   ttid  = (const int*)d_in[1];    // [32,512]
    const int*   amask = (const int*)d_in[2];    // [32,512]
    const float* W     = (const float*)d_in[3];  // [512,1]
    const float* biasp = (const float*)d_in[4];  // [1]
    float*       out   = (float*)d_out;          // [32,4068]

    float2* sed = (float2*)d_ws;                 // 16384 float2

    dot_kernel<<<dim3(4096), dim3(256), 0, stream>>>(emb, ttid, amask, W, sed);
    softmax_kernel<<<dim3(32), dim3(1024), 0, stream>>>(
        (const float*)sed, biasp, out);
}